// Round 14
// baseline (123.468 us; speedup 1.0000x reference)
//
#include <hip/hip_runtime.h>
#include <math.h>

#define S_LEN 1024
#define DIMS  1024
#define NHEAD 16
#define HD    64
#define BATCH 2
#define MROWS (BATCH * S_LEN)   // 2048
#define LOG2E 1.44269504088896f

typedef unsigned short us;
typedef __attribute__((ext_vector_type(8))) __bf16 bf8_t;
typedef __attribute__((ext_vector_type(8))) unsigned short us8_t;
typedef __attribute__((ext_vector_type(4))) unsigned short us4_t;
typedef __attribute__((ext_vector_type(4))) float f32x4;
typedef __attribute__((ext_vector_type(4))) unsigned int u32x4;

static __device__ inline us f2bf(float f) {
    unsigned int u = __builtin_bit_cast(unsigned int, f);
    unsigned int r = u + 0x7fffu + ((u >> 16) & 1u);
    return (us)(r >> 16);
}
static __device__ inline float bf2f(us v) {
    unsigned int u = ((unsigned int)v) << 16;
    return __builtin_bit_cast(float, u);
}
static __device__ inline unsigned int pk2bf(float lo, float hi) {
    unsigned int r;
    asm("v_cvt_pk_bf16_f32 %0, %1, %2" : "=v"(r) : "v"(lo), "v"(hi));
    return r;
}
static __device__ inline f32x4 mfma16(us8_t a, us8_t b, f32x4 c) {
    return __builtin_amdgcn_mfma_f32_16x16x32_bf16(
        __builtin_bit_cast(bf8_t, a), __builtin_bit_cast(bf8_t, b), c, 0, 0, 0);
}

// -------- prep: 5 weight converts + both LayerNorms + span-counter zero -----
__global__ __launch_bounds__(256) void prep_kernel(
    const float* __restrict__ s0, const float* __restrict__ s1,
    const float* __restrict__ s2, const float* __restrict__ s3,
    const float* __restrict__ s4,
    us* __restrict__ d0, us* __restrict__ d1, us* __restrict__ d2,
    us* __restrict__ d3, us* __restrict__ d4,
    const float* __restrict__ x,
    const float* __restrict__ ga, const float* __restrict__ ba,
    const float* __restrict__ gb, const float* __restrict__ bb,
    us* __restrict__ outA, us* __restrict__ outB,
    unsigned int* __restrict__ ctr)
{
    int bidx = blockIdx.x;
    int t = threadIdx.x;
    if (bidx == 0 && t == 0) *ctr = 0u;
    if (bidx < 6144) {
        const float* src; us* dst; int blk;
        if (bidx < 1024)      { src = s0; dst = d0; blk = bidx; }
        else if (bidx < 2048) { src = s1; dst = d1; blk = bidx - 1024; }
        else if (bidx < 3072) { src = s2; dst = d2; blk = bidx - 2048; }
        else if (bidx < 4096) { src = s3; dst = d3; blk = bidx - 3072; }
        else                  { src = s4; dst = d4; blk = bidx - 4096; }
        size_t idx = (size_t)blk * 1024 + t * 4;
        float4 v = *(const float4*)(src + idx);
        us4_t ot;
        ot[0] = f2bf(v.x); ot[1] = f2bf(v.y); ot[2] = f2bf(v.z); ot[3] = f2bf(v.w);
        *(us4_t*)(dst + idx) = ot;
        return;
    }
    int row = bidx - 6144;
    const float* xr = x + (size_t)row * DIMS;
    float4 v = *(const float4*)(xr + t * 4);
    float sum1 = v.x + v.y + v.z + v.w;
    float sumq = v.x * v.x + v.y * v.y + v.z * v.z + v.w * v.w;
#pragma unroll
    for (int o = 32; o > 0; o >>= 1) {
        sum1 += __shfl_down(sum1, o, 64);
        sumq += __shfl_down(sumq, o, 64);
    }
    __shared__ float rs[4], rq[4];
    int wid = t >> 6, lane = t & 63;
    if (lane == 0) { rs[wid] = sum1; rq[wid] = sumq; }
    __syncthreads();
    float T1 = rs[0] + rs[1] + rs[2] + rs[3];
    float T2 = rq[0] + rq[1] + rq[2] + rq[3];
    float mean = T1 * (1.0f / DIMS);
    float var  = T2 * (1.0f / DIMS) - mean * mean;
    float inv  = 1.0f / sqrtf(var + 1e-5f);
    float4 vga = *(const float4*)(ga + t * 4);
    float4 vba = *(const float4*)(ba + t * 4);
    float4 vgb = *(const float4*)(gb + t * 4);
    float4 vbb = *(const float4*)(bb + t * 4);
    float nx = (v.x - mean) * inv, ny = (v.y - mean) * inv;
    float nz = (v.z - mean) * inv, nw = (v.w - mean) * inv;
    us4_t oa, ob;
    oa[0] = f2bf(nx * vga.x + vba.x); oa[1] = f2bf(ny * vga.y + vba.y);
    oa[2] = f2bf(nz * vga.z + vba.z); oa[3] = f2bf(nw * vga.w + vba.w);
    ob[0] = f2bf(nx * vgb.x + vbb.x); ob[1] = f2bf(ny * vgb.y + vbb.y);
    ob[2] = f2bf(nz * vgb.z + vbb.z); ob[3] = f2bf(nw * vgb.w + vbb.w);
    *(us4_t*)(outA + (size_t)row * DIMS + t * 4) = oa;
    *(us4_t*)(outB + (size_t)row * DIMS + t * 4) = ob;
}

// ------------- bf16 MFMA GEMM, BM=128 BN=64 BK=64, 4 waves (64x32/wave) ----
static __device__ __forceinline__ void gemm128_body(
    const us* __restrict__ A, int lda,
    const us* __restrict__ W, int ldw,
    const float* __restrict__ bias,
    us* __restrict__ Cp, int ldc, int K,
    int bm, int bn, us* As, us* Bs)
{
    int tid = threadIdx.x;
    int w = tid >> 6, l = tid & 63, l15 = l & 15, lhi = l >> 4;
    int wr = w >> 1, wc = w & 1;
    f32x4 acc[4][2];
#pragma unroll
    for (int m = 0; m < 4; ++m) { acc[m][0] = (f32x4){0,0,0,0}; acc[m][1] = (f32x4){0,0,0,0}; }
    int srow = tid >> 3;
    int scol8 = tid & 7;
    int sl = (scol8 ^ (srow & 7)) * 8;
    const us* Ap = A + (size_t)(bm + srow) * lda + scol8 * 8;
    const us* Wpt = W + (size_t)(bn + srow) * ldw + scol8 * 8;
    us8_t a0 = *(const us8_t*)(Ap);
    us8_t a1 = *(const us8_t*)(Ap + (size_t)32 * lda);
    us8_t a2 = *(const us8_t*)(Ap + (size_t)64 * lda);
    us8_t a3 = *(const us8_t*)(Ap + (size_t)96 * lda);
    us8_t b0 = *(const us8_t*)(Wpt);
    us8_t b1 = *(const us8_t*)(Wpt + (size_t)32 * ldw);
    for (int kt = 0; kt < K; kt += 64) {
        __syncthreads();
        *(us8_t*)&As[(srow +  0) * 64 + sl] = a0;
        *(us8_t*)&As[(srow + 32) * 64 + sl] = a1;
        *(us8_t*)&As[(srow + 64) * 64 + sl] = a2;
        *(us8_t*)&As[(srow + 96) * 64 + sl] = a3;
        *(us8_t*)&Bs[(srow +  0) * 64 + sl] = b0;
        *(us8_t*)&Bs[(srow + 32) * 64 + sl] = b1;
        __syncthreads();
        if (kt + 64 < K) {
            a0 = *(const us8_t*)(Ap + kt + 64);
            a1 = *(const us8_t*)(Ap + (size_t)32 * lda + kt + 64);
            a2 = *(const us8_t*)(Ap + (size_t)64 * lda + kt + 64);
            a3 = *(const us8_t*)(Ap + (size_t)96 * lda + kt + 64);
            b0 = *(const us8_t*)(Wpt + kt + 64);
            b1 = *(const us8_t*)(Wpt + (size_t)32 * ldw + kt + 64);
        }
#pragma unroll
        for (int kk = 0; kk < 2; ++kk) {
            int xo = ((kk * 4 + lhi) ^ (l15 & 7)) * 8;
            us8_t af[4], bfr[2];
#pragma unroll
            for (int m = 0; m < 4; ++m)
                af[m] = *(const us8_t*)&As[(wr * 64 + m * 16 + l15) * 64 + xo];
#pragma unroll
            for (int n = 0; n < 2; ++n)
                bfr[n] = *(const us8_t*)&Bs[(wc * 32 + n * 16 + l15) * 64 + xo];
#pragma unroll
            for (int m = 0; m < 4; ++m)
#pragma unroll
                for (int n = 0; n < 2; ++n)
                    acc[m][n] = mfma16(af[m], bfr[n], acc[m][n]);
        }
    }
    float bvv[2] = {0.f, 0.f};
    if (bias) {
#pragma unroll
        for (int n = 0; n < 2; ++n)
            bvv[n] = bias[bn + wc * 32 + n * 16 + l15];
    }
#pragma unroll
    for (int m = 0; m < 4; ++m) {
#pragma unroll
        for (int n = 0; n < 2; ++n) {
            int row = bm + wr * 64 + m * 16 + lhi * 4;
            int col = bn + wc * 32 + n * 16 + l15;
            unsigned int p01 = pk2bf(acc[m][n][0] + bvv[n], acc[m][n][1] + bvv[n]);
            unsigned int p23 = pk2bf(acc[m][n][2] + bvv[n], acc[m][n][3] + bvv[n]);
            Cp[(size_t)(row + 0) * ldc + col] = (us)p01;
            Cp[(size_t)(row + 1) * ldc + col] = (us)(p01 >> 16);
            Cp[(size_t)(row + 2) * ldc + col] = (us)p23;
            Cp[(size_t)(row + 3) * ldc + col] = (us)(p23 >> 16);
        }
    }
}

// q,k,v in one launch: blockIdx.x selects matrix (16 n-tiles each)
__global__ __launch_bounds__(256) void gemm_qkv(
    const us* __restrict__ A,
    const us* __restrict__ Wq, const us* __restrict__ Wk, const us* __restrict__ Wv,
    const float* __restrict__ bq, const float* __restrict__ bv,
    us* __restrict__ qo, us* __restrict__ ko, us* __restrict__ vo)
{
    __shared__ __align__(16) us As[128 * 64];
    __shared__ __align__(16) us Bs[64 * 64];
    int which = blockIdx.x >> 4;
    int bn = (blockIdx.x & 15) * 64, bm = blockIdx.y * 128;
    const us* W = (which == 0) ? Wq : ((which == 1) ? Wk : Wv);
    const float* bias2 = (which == 0) ? bq : ((which == 2) ? bv : nullptr);
    us* Out = (which == 0) ? qo : ((which == 1) ? ko : vo);
    gemm128_body(A, DIMS, W, DIMS, bias2, Out, DIMS, DIMS, bm, bn, As, Bs);
}

// ---------------- 64x64-tile GEMM, bf16 out (Wc) ---------------------------
__global__ __launch_bounds__(256) void gemm_bf16out(
    const us* __restrict__ A, int lda,
    const us* __restrict__ W, int ldw,
    const float* __restrict__ bias,
    us* __restrict__ Cp, int ldc, int K)
{
    __shared__ __align__(16) us As[64 * 64];
    __shared__ __align__(16) us Bs[64 * 64];
    int tid = threadIdx.x;
    int w = tid >> 6, l = tid & 63, l15 = l & 15, lhi = l >> 4;
    int wr = w >> 1, wc = w & 1;
    int bm = blockIdx.y * 64, bn = blockIdx.x * 64;
    f32x4 acc[2][2] = {{{0,0,0,0},{0,0,0,0}},{{0,0,0,0},{0,0,0,0}}};
    int srow = tid >> 3;
    int scol8 = tid & 7;
    const us* Ap = A + (size_t)(bm + srow) * lda + scol8 * 8;
    const us* Wpt = W + (size_t)(bn + srow) * ldw + scol8 * 8;
    int sl = (scol8 ^ (srow & 7)) * 8;
    us8_t a0 = *(const us8_t*)(Ap);
    us8_t a1 = *(const us8_t*)(Ap + (size_t)32 * lda);
    us8_t b0 = *(const us8_t*)(Wpt);
    us8_t b1 = *(const us8_t*)(Wpt + (size_t)32 * ldw);
    for (int kt = 0; kt < K; kt += 64) {
        __syncthreads();
        *(us8_t*)&As[srow * 64 + sl] = a0;
        *(us8_t*)&As[(srow + 32) * 64 + sl] = a1;
        *(us8_t*)&Bs[srow * 64 + sl] = b0;
        *(us8_t*)&Bs[(srow + 32) * 64 + sl] = b1;
        __syncthreads();
        if (kt + 64 < K) {
            a0 = *(const us8_t*)(Ap + kt + 64);
            a1 = *(const us8_t*)(Ap + (size_t)32 * lda + kt + 64);
            b0 = *(const us8_t*)(Wpt + kt + 64);
            b1 = *(const us8_t*)(Wpt + (size_t)32 * ldw + kt + 64);
        }
#pragma unroll
        for (int kk = 0; kk < 2; ++kk) {
            int xo = ((kk * 4 + lhi) ^ (l15 & 7)) * 8;
            us8_t af[2], bfr[2];
#pragma unroll
            for (int m = 0; m < 2; ++m)
                af[m] = *(const us8_t*)&As[(wr * 32 + m * 16 + l15) * 64 + xo];
#pragma unroll
            for (int n = 0; n < 2; ++n)
                bfr[n] = *(const us8_t*)&Bs[(wc * 32 + n * 16 + l15) * 64 + xo];
#pragma unroll
            for (int m = 0; m < 2; ++m)
#pragma unroll
                for (int n = 0; n < 2; ++n)
                    acc[m][n] = mfma16(af[m], bfr[n], acc[m][n]);
        }
    }
    float bvv[2];
#pragma unroll
    for (int n = 0; n < 2; ++n)
        bvv[n] = bias[bn + wc * 32 + n * 16 + l15];
#pragma unroll
    for (int m = 0; m < 2; ++m) {
#pragma unroll
        for (int n = 0; n < 2; ++n) {
            int row = bm + wr * 32 + m * 16 + lhi * 4;
            int col = bn + wc * 32 + n * 16 + l15;
            unsigned int p01 = pk2bf(acc[m][n][0] + bvv[n], acc[m][n][1] + bvv[n]);
            unsigned int p23 = pk2bf(acc[m][n][2] + bvv[n], acc[m][n][3] + bvv[n]);
            Cp[(size_t)(row + 0) * ldc + col] = (us)p01;
            Cp[(size_t)(row + 1) * ldc + col] = (us)(p01 >> 16);
            Cp[(size_t)(row + 2) * ldc + col] = (us)p23;
            Cp[(size_t)(row + 3) * ldc + col] = (us)(p23 >> 16);
        }
    }
}

// ---------------- 64x64-tile GEMM, f32 out (Wo) ----------------------------
__global__ __launch_bounds__(256) void gemm_f32out(
    const us* __restrict__ A, int lda,
    const us* __restrict__ W, int ldw,
    const float* __restrict__ bias,
    float* __restrict__ Cp, int ldc, int K)
{
    __shared__ __align__(16) us As[64 * 64];
    __shared__ __align__(16) us Bs[64 * 64];
    int tid = threadIdx.x;
    int w = tid >> 6, l = tid & 63, l15 = l & 15, lhi = l >> 4;
    int wr = w >> 1, wc = w & 1;
    int bm = blockIdx.y * 64, bn = blockIdx.x * 64;
    f32x4 acc[2][2] = {{{0,0,0,0},{0,0,0,0}},{{0,0,0,0},{0,0,0,0}}};
    int srow = tid >> 3;
    int scol8 = tid & 7;
    const us* Ap = A + (size_t)(bm + srow) * lda + scol8 * 8;
    const us* Wpt = W + (size_t)(bn + srow) * ldw + scol8 * 8;
    int sl = (scol8 ^ (srow & 7)) * 8;
    us8_t a0 = *(const us8_t*)(Ap);
    us8_t a1 = *(const us8_t*)(Ap + (size_t)32 * lda);
    us8_t b0 = *(const us8_t*)(Wpt);
    us8_t b1 = *(const us8_t*)(Wpt + (size_t)32 * ldw);
    for (int kt = 0; kt < K; kt += 64) {
        __syncthreads();
        *(us8_t*)&As[srow * 64 + sl] = a0;
        *(us8_t*)&As[(srow + 32) * 64 + sl] = a1;
        *(us8_t*)&Bs[srow * 64 + sl] = b0;
        *(us8_t*)&Bs[(srow + 32) * 64 + sl] = b1;
        __syncthreads();
        if (kt + 64 < K) {
            a0 = *(const us8_t*)(Ap + kt + 64);
            a1 = *(const us8_t*)(Ap + (size_t)32 * lda + kt + 64);
            b0 = *(const us8_t*)(Wpt + kt + 64);
            b1 = *(const us8_t*)(Wpt + (size_t)32 * ldw + kt + 64);
        }
#pragma unroll
        for (int kk = 0; kk < 2; ++kk) {
            int xo = ((kk * 4 + lhi) ^ (l15 & 7)) * 8;
            us8_t af[2], bfr[2];
#pragma unroll
            for (int m = 0; m < 2; ++m)
                af[m] = *(const us8_t*)&As[(wr * 32 + m * 16 + l15) * 64 + xo];
#pragma unroll
            for (int n = 0; n < 2; ++n)
                bfr[n] = *(const us8_t*)&Bs[(wc * 32 + n * 16 + l15) * 64 + xo];
#pragma unroll
            for (int m = 0; m < 2; ++m)
#pragma unroll
                for (int n = 0; n < 2; ++n)
                    acc[m][n] = mfma16(af[m], bfr[n], acc[m][n]);
        }
    }
    float bvv[2];
#pragma unroll
    for (int n = 0; n < 2; ++n)
        bvv[n] = bias[bn + wc * 32 + n * 16 + l15];
#pragma unroll
    for (int m = 0; m < 2; ++m) {
#pragma unroll
        for (int n = 0; n < 2; ++n) {
            int row = bm + wr * 32 + m * 16 + lhi * 4;
            int col = bn + wc * 32 + n * 16 + l15;
#pragma unroll
            for (int r = 0; r < 4; ++r)
                Cp[(size_t)(row + r) * ldc + col] = acc[m][n][r] + bvv[n];
        }
    }
}

// ------- MFMA flash attention, split-K, 8 waves, Pt + tr-read, XCD map -----
// Iteration-parity double-buffered Ks/Vt: ONE barrier per key-tile iteration.
// Safety: a wave's reads of buf[p] at iter i-1 are consumed by its MFMAs
// before it reaches barrier(i) (data dep + waitcnt); the next write to
// buf[p] (iter i+1) occurs only after barrier(i) -> no read/write race.
template <int LOCAL>
__global__ __launch_bounds__(512) void attn_mfma(
    const us* __restrict__ Q, const us* __restrict__ K,
    const us* __restrict__ V, us* __restrict__ O, int ldo,
    const float* __restrict__ span)
{
    __shared__ __align__(16) us Ks[2][2][64 * 64];  // [iter&1][half][key][d]
    __shared__ __align__(16) us Vt[2][2][64 * 64];  // [iter&1][half][d][key]
    __shared__ __align__(16) us Ps[8][1024];        // per-wave P, tr-read layout

    int bid = blockIdx.x;
    int xcd = bid & 7, slot = bid >> 3;
    int p = xcd + 8 * (slot >> 4);
    int q0blk = (slot & 15) * 64;
    int h = p & 15, b = p >> 4;

    int tid = threadIdx.x;
    int w = tid >> 6, l = tid & 63;
    int l15 = l & 15, lhi = l >> 4;
    int wq = w & 3, wk = w >> 2;

    float scale; int eff;
    if (LOCAL) { scale = span[1] * LOG2E; eff = (int)span[0]; }
    else       { scale = LOG2E / 64.0f; eff = S_LEN; }
    int ntiles = LOCAL ? ((eff + 63) >> 6) : 16;
    int nIter = (ntiles + 1) >> 1;

    int qrow = q0blk + wq * 16 + l15;
    const us* qptr = Q + ((size_t)(b * S_LEN + qrow)) * DIMS + h * HD + lhi * 8;
    us8_t qf[2];
    qf[0] = *(const us8_t*)(qptr);
    qf[1] = *(const us8_t*)(qptr + 32);

    f32x4 o[4] = {{0,0,0,0},{0,0,0,0},{0,0,0,0},{0,0,0,0}};
    float m_r[4] = {-1e30f, -1e30f, -1e30f, -1e30f};
    float l_r[4] = {0.f, 0.f, 0.f, 0.f};

    int half = tid >> 8;
    int t0 = tid & 255;
    int krow = t0 >> 3, kcol8 = t0 & 7;
    int ksl = (kcol8 ^ (krow & 7)) * 8;
    int vkb = t0 & 15, vdb = t0 >> 4;
    const us* Kb = K + ((size_t)(b * S_LEN)) * DIMS + h * HD;
    const us* Vb = V + ((size_t)(b * S_LEN)) * DIMS + h * HD;

    unsigned pbase = (unsigned)(unsigned long long)&Ps[w][0];
    unsigned paddr = pbase + (unsigned)(l * 8);

    us8_t kc0, kc1;
    us4_t vr0, vr1, vr2, vr3;
    if (half < ntiles) {
        const us* kp = Kb + (size_t)(half * 64 + krow) * DIMS + kcol8 * 8;
        kc0 = *(const us8_t*)kp;
        kc1 = *(const us8_t*)(kp + (size_t)32 * DIMS);
        const us* vp = Vb + (size_t)(half * 64 + vkb * 4) * DIMS + vdb * 4;
        vr0 = *(const us4_t*)(vp);
        vr1 = *(const us4_t*)(vp + DIMS);
        vr2 = *(const us4_t*)(vp + 2 * DIMS);
        vr3 = *(const us4_t*)(vp + 3 * DIMS);
    }

    for (int i = 0; i < nIter; ++i) {
        int ib = i & 1;
        // write prefetched regs into this iteration's buffer (before barrier)
        if (2 * i + half < ntiles) {
            *(us8_t*)&Ks[ib][half][krow * 64 + ksl] = kc0;
            *(us8_t*)&Ks[ib][half][(krow + 32) * 64 + ksl] = kc1;
#pragma unroll
            for (int j = 0; j < 4; ++j) {
                int d = vdb * 4 + j;
                us4_t wv;
                wv[0] = vr0[j]; wv[1] = vr1[j]; wv[2] = vr2[j]; wv[3] = vr3[j];
                int slotv = (vkb >> 1) ^ (d & 7);
                *(us4_t*)&Vt[ib][half][d * 64 + slotv * 8 + (vkb & 1) * 4] = wv;
            }
        }
        __syncthreads();   // single barrier: staged tiles visible
        int nt2 = 2 * (i + 1) + half;
        if (nt2 < ntiles) {   // issue next loads; latency hides under compute
            const us* kp = Kb + (size_t)(nt2 * 64 + krow) * DIMS + kcol8 * 8;
            kc0 = *(const us8_t*)kp;
            kc1 = *(const us8_t*)(kp + (size_t)32 * DIMS);
            const us* vp = Vb + (size_t)(nt2 * 64 + vkb * 4) * DIMS + vdb * 4;
            vr0 = *(const us4_t*)(vp);
            vr1 = *(const us4_t*)(vp + DIMS);
            vr2 = *(const us4_t*)(vp + 2 * DIMS);
            vr3 = *(const us4_t*)(vp + 3 * DIMS);
        }
        int kt = 2 * i + wk;
        if (kt < ntiles) {
            f32x4 s4[4] = {{0,0,0,0},{0,0,0,0},{0,0,0,0},{0,0,0,0}};
            __builtin_amdgcn_s_setprio(1);
#pragma unroll
            for (int kk = 0; kk < 2; ++kk) {
                int xo = ((kk * 4 + lhi) ^ (l15 & 7)) * 8;
#pragma unroll
                for (int n = 0; n < 4; ++n) {
                    us8_t bk = *(const us8_t*)&Ks[ib][wk][(n * 16 + l15) * 64 + xo];
                    s4[n] = mfma16(qf[kk], bk, s4[n]);
                }
            }
            __builtin_amdgcn_s_setprio(0);
#pragma unroll
            for (int n = 0; n < 4; ++n) {
                s4[n] *= scale;
                if (LOCAL) {
                    int key = kt * 64 + n * 16 + l15;
                    if (key >= eff) {
                        s4[n][0] = -1e30f; s4[n][1] = -1e30f;
                        s4[n][2] = -1e30f; s4[n][3] = -1e30f;
                    }
                }
            }
            float tl[4];
#pragma unroll
            for (int r = 0; r < 4; ++r)
                tl[r] = fmaxf(fmaxf(s4[0][r], s4[1][r]), fmaxf(s4[2][r], s4[3][r]));
            int ex = (tl[0] > m_r[0] + 11.5f) | (tl[1] > m_r[1] + 11.5f) |
                     (tl[2] > m_r[2] + 11.5f) | (tl[3] > m_r[3] + 11.5f);
            if (__any(ex)) {
#pragma unroll
                for (int msk = 1; msk <= 8; msk <<= 1) {
#pragma unroll
                    for (int r = 0; r < 4; ++r)
                        tl[r] = fmaxf(tl[r], __shfl_xor(tl[r], msk, 64));
                }
                float fac[4];
#pragma unroll
                for (int r = 0; r < 4; ++r) {
                    float mn = fmaxf(m_r[r], tl[r]);
                    fac[r] = exp2f(m_r[r] - mn);
                    m_r[r] = mn;
                    l_r[r] *= fac[r];
                }
#pragma unroll
                for (int n = 0; n < 4; ++n) {
                    o[n][0] *= fac[0]; o[n][1] *= fac[1];
                    o[n][2] *= fac[2]; o[n][3] *= fac[3];
                }
            }
#pragma unroll
            for (int n = 0; n < 4; ++n) {
                float p0 = exp2f(s4[n][0] - m_r[0]);
                float p1 = exp2f(s4[n][1] - m_r[1]);
                float p2 = exp2f(s4[n][2] - m_r[2]);
                float p3 = exp2f(s4[n][3] - m_r[3]);
                l_r[0] += p0; l_r[1] += p1; l_r[2] += p2; l_r[3] += p3;
                unsigned int p01 = pk2bf(p0, p1);
                unsigned int p23 = pk2bf(p2, p3);
                int idx = (n >> 1) * 512 + ((l15 & 4) ? 256 : 0)
                        + ((n & 1) * 2 + (l15 >> 3)) * 64 + (l15 & 3) * 16 + lhi * 4;
                *(uint2*)&Ps[w][idx] = make_uint2(p01, p23);
            }
            unsigned long long ta0, ta1, ta2, ta3;
            asm volatile(
                "ds_read_b64_tr_b16 %0, %4\n\t"
                "ds_read_b64_tr_b16 %1, %4 offset:512\n\t"
                "ds_read_b64_tr_b16 %2, %4 offset:1024\n\t"
                "ds_read_b64_tr_b16 %3, %4 offset:1536\n\t"
                "s_waitcnt lgkmcnt(0)"
                : "=&v"(ta0), "=&v"(ta1), "=&v"(ta2), "=&v"(ta3)
                : "v"(paddr)
                : "memory");
            __builtin_amdgcn_sched_barrier(0);
            u32x4 w0 = {(unsigned)ta0, (unsigned)(ta0 >> 32),
                        (unsigned)ta1, (unsigned)(ta1 >> 32)};
            u32x4 w1 = {(unsigned)ta2, (unsigned)(ta2 >> 32),
                        (unsigned)ta3, (unsigned)(ta3 >> 32)};
            us8_t pa0 = __builtin_bit_cast(us8_t, w0);
            us8_t pa1 = __builtin_bit_cast(us8_t, w1);
            __builtin_amdgcn_s_setprio(1);
#pragma unroll
            for (int kk = 0; kk < 2; ++kk) {
                int xo = ((kk * 4 + lhi) ^ (l15 & 7)) * 8;
                us8_t pa = kk ? pa1 : pa0;
#pragma unroll
                for (int n = 0; n < 4; ++n) {
                    us8_t vb = *(const us8_t*)&Vt[ib][wk][(n * 16 + l15) * 64 + xo];
                    o[n] = mfma16(pa, vb, o[n]);
                }
            }
            __builtin_amdgcn_s_setprio(0);
        }
    }

#pragma unroll
    for (int msk = 1; msk <= 8; msk <<= 1) {
#pragma unroll
        for (int r = 0; r < 4; ++r)
            l_r[r] += __shfl_xor(l_r[r], msk, 64);
    }

    __syncthreads();
    float* obuf = (float*)&Ks[0][0][0];
    float* mlb  = (float*)&Vt[0][0][0];
    if (wk == 1) {
#pragma unroll
        for (int n = 0; n < 4; ++n)
#pragma unroll
            for (int r = 0; r < 4; ++r)
                obuf[wq * 1024 + (lhi * 4 + r) * 64 + n * 16 + l15] = o[n][r];
        if (l15 == 0) {
#pragma unroll
            for (int r = 0; r < 4; ++r) {
                mlb[wq * 32 + (lhi * 4 + r) * 2 + 0] = m_r[r];
                mlb[wq * 32 + (lhi * 4 + r) * 2 + 1] = l_r[r];
            }
        }
    }
    __syncthreads();
    if (wk == 0) {
        float f0[4], f1[4], rcp[4];
#pragma unroll
        for (int r = 0; r < 4; ++r) {
            int row = lhi * 4 + r;
            float m1 = mlb[wq * 32 + row * 2 + 0];
            float l1 = mlb[wq * 32 + row * 2 + 1];
            float ms = fmaxf(m_r[r], m1);
            f0[r] = exp2f(m_r[r] - ms);
            f1[r] = exp2f(m1 - ms);
            rcp[r] = 1.0f / (l_r[r] * f0[r] + l1 * f1[r]);
        }
#pragma unroll
        for (int n = 0; n < 4; ++n) {
            float vv[4];
#pragma unroll
            for (int r = 0; r < 4; ++r) {
                int row = q0blk + wq * 16 + lhi * 4 + r;
                float val = (o[n][r] * f0[r] +
                             obuf[wq * 1024 + (lhi * 4 + r) * 64 + n * 16 + l15] * f1[r]) * rcp[r];
                if (LOCAL && row >= eff) val = 0.0f;
                vv[r] = val;
            }
            int row0 = q0blk + wq * 16 + lhi * 4;
            unsigned int p01 = pk2bf(vv[0], vv[1]);
            unsigned int p23 = pk2bf(vv[2], vv[3]);
            size_t base = ((size_t)(b * S_LEN + row0)) * ldo + h * HD + n * 16 + l15;
            O[base + 0 * ldo] = (us)p01;
            O[base + 1 * ldo] = (us)(p01 >> 16);
            O[base + 2 * ldo] = (us)p23;
            O[base + 3 * ldo] = (us)(p23 >> 16);
        }
    }
}

// ------- span predictor, fused (64 blocks; last block finalizes) -----------
__global__ __launch_bounds__(256) void span_fused(
    const us* __restrict__ gout, const float* __restrict__ Wp,
    const float* __restrict__ bp,
    float* __restrict__ partials, float* __restrict__ spanbuf,
    unsigned int* __restrict__ ctr)
{
    int slice = blockIdx.x;   // 0..31, 32 rows each
    int b = blockIdx.y;
    int t = threadIdx.x;
    float4 wp = *(const float4*)(Wp + t * 4);
    float acc = 0;
    int srow0 = slice * 32;
    for (int s = srow0; s < srow0 + 32; ++s) {
        us4_t g = *(const us4_t*)(gout + (size_t)(b * S_LEN + s) * 2048 + t * 4);
        acc += bf2f(g[0]) * wp.x + bf2f(g[1]) * wp.y + bf2f(g[2]) * wp.z + bf2f(g[3]) * wp.w;
    }
#pragma unroll
    for (int o = 32; o > 0; o >>= 1) acc += __shfl_down(acc, o, 64);
    __shared__ float r[4];
    int wid = t >> 6, lane = t & 63;
    if (lane == 0) r[wid] = acc;
    __syncthreads();
    if (t == 0) {
        partials[b * 32 + slice] = r[0] + r[1] + r[2] + r[3];
        __threadfence();
        unsigned int old = atomicAdd(ctr, 1u);
        if (old == 63u) {
            __threadfence();
            float l0 = 0, l1 = 0;
            for (int i = 0; i < 32; ++i) { l0 += partials[i]; l1 += partials[32 + i]; }
            l0 = l0 * (1.0f / 1024.0f) + bp[0];
            l1 = l1 * (1.0f / 1024.0f) + bp[0];
            float sg0 = 1.0f / (1.0f + expf(-l0));
            float sg1 = 1.0f / (1.0f + expf(-l1));
            float sm = 0.5f * (sg0 + sg1);
            int sl = (int)floorf(1024.0f * sm);
            int eff = sl; if (eff > 1024) eff = 1024; if (eff < 1) eff = 1;
            float temp = 1.0f + 0.01f * (1.0f - sm);
            spanbuf[0] = (float)eff;
            spanbuf[1] = 0.35355339059327378f / temp;  // 64^-0.25 / temp
        }
    }
}

extern "C" void kernel_launch(void* const* d_in, const int* in_sizes, int n_in,
                              void* d_out, int out_size, void* d_ws, size_t ws_size,
                              hipStream_t stream)
{
    (void)in_sizes; (void)n_in; (void)out_size; (void)ws_size;
    const float* x   = (const float*)d_in[0];
    const float* lag = (const float*)d_in[1];
    const float* lab = (const float*)d_in[2];
    const float* lbg = (const float*)d_in[3];
    const float* lbb = (const float*)d_in[4];
    const float* Wq  = (const float*)d_in[5];
    const float* bq  = (const float*)d_in[6];
    const float* Wk  = (const float*)d_in[7];
    const float* Wv  = (const float*)d_in[8];
    const float* bv  = (const float*)d_in[9];
    const float* Wc  = (const float*)d_in[10];
    const float* bc  = (const float*)d_in[11];
    const float* Wp  = (const float*)d_in[12];
    const float* bp  = (const float*)d_in[13];
    const float* Wo  = (const float*)d_in[14];
    const float* bo  = (const float*)d_in[15];
    float* out = (float*)d_out;
    us* wsu = (us*)d_ws;

    const size_t NM = (size_t)MROWS * DIMS;      // 2M elements
    us* lnAbf = wsu;
    us* lnBbf = wsu + NM;
    us* gattbf = lnBbf;
    us* qbf   = wsu + 2 * NM;
    us* kbf   = wsu + 3 * NM;
    us* vbf   = wsu + 4 * NM;
    us* combbf = qbf;                // [2048,2048] bf16
    us* Wqbf  = wsu + 5 * NM;
    us* Wkbf  = Wqbf + DIMS * DIMS;
    us* Wvbf  = Wkbf + DIMS * DIMS;
    us* Wcbf  = Wvbf + DIMS * DIMS;
    us* Wobf  = Wcbf + DIMS * DIMS;
    float* partials = (float*)(Wobf + 2 * DIMS * DIMS);   // 64 floats
    float* spanbuf  = partials + 64;
    unsigned int* spanctr = (unsigned int*)(spanbuf + 8);

    // weights cvt + both LNs + counter zero, one launch
    prep_kernel<<<8192, 256, 0, stream>>>(Wq, Wk, Wv, Wc, Wo,
                                          Wqbf, Wkbf, Wvbf, Wcbf, Wobf,
                                          x, lag, lab, lbg, lbb, lnAbf, lnBbf,
                                          spanctr);

    gemm_qkv<<<dim3(48, MROWS / 128), 256, 0, stream>>>(
        lnBbf, Wqbf, Wkbf, Wvbf, bq, bv, qbf, kbf, vbf);

    attn_mfma<0><<<512, 512, 0, stream>>>(qbf, kbf, vbf, gattbf, DIMS, nullptr);

    // g_out -> comb[:, 1024:2048]  (bf16)
    gemm_bf16out<<<dim3(DIMS / 64, MROWS / 64), 256, 0, stream>>>(
        gattbf, DIMS, Wcbf, DIMS, bc, combbf + 1024, 2048, DIMS);

    span_fused<<<dim3(32, BATCH), 256, 0, stream>>>(combbf + 1024, Wp, bp,
                                                    partials, spanbuf, spanctr);

    // l_out -> comb[:, 0:1024]  (bf16)
    attn_mfma<1><<<512, 512, 0, stream>>>(lnAbf, lnAbf, lnAbf, combbf, 2048, spanbuf);

    // out = comb @ Wo^T + bo   (K = 2048, f32 out)
    gemm_f32out<<<dim3(DIMS / 64, MROWS / 64), 256, 0, stream>>>(
        combbf, 2048, Wobf, 2048, bo, out, DIMS, 2 * DIMS);
}

// Round 15
// 122.673 us; speedup vs baseline: 1.0065x; 1.0065x over previous
//
#include <hip/hip_runtime.h>
#include <math.h>

#define S_LEN 1024
#define DIMS  1024
#define NHEAD 16
#define HD    64
#define BATCH 2
#define MROWS (BATCH * S_LEN)   // 2048
#define LOG2E 1.44269504088896f

typedef unsigned short us;
typedef __attribute__((ext_vector_type(8))) __bf16 bf8_t;
typedef __attribute__((ext_vector_type(8))) unsigned short us8_t;
typedef __attribute__((ext_vector_type(4))) unsigned short us4_t;
typedef __attribute__((ext_vector_type(4))) float f32x4;
typedef __attribute__((ext_vector_type(4))) unsigned int u32x4;

static __device__ inline us f2bf(float f) {
    unsigned int u = __builtin_bit_cast(unsigned int, f);
    unsigned int r = u + 0x7fffu + ((u >> 16) & 1u);
    return (us)(r >> 16);
}
static __device__ inline float bf2f(us v) {
    unsigned int u = ((unsigned int)v) << 16;
    return __builtin_bit_cast(float, u);
}
static __device__ inline unsigned int pk2bf(float lo, float hi) {
    unsigned int r;
    asm("v_cvt_pk_bf16_f32 %0, %1, %2" : "=v"(r) : "v"(lo), "v"(hi));
    return r;
}
static __device__ inline f32x4 mfma16(us8_t a, us8_t b, f32x4 c) {
    return __builtin_amdgcn_mfma_f32_16x16x32_bf16(
        __builtin_bit_cast(bf8_t, a), __builtin_bit_cast(bf8_t, b), c, 0, 0, 0);
}

// -------- prep: 5 weight converts + both LayerNorms + span-counter zero -----
__global__ __launch_bounds__(256) void prep_kernel(
    const float* __restrict__ s0, const float* __restrict__ s1,
    const float* __restrict__ s2, const float* __restrict__ s3,
    const float* __restrict__ s4,
    us* __restrict__ d0, us* __restrict__ d1, us* __restrict__ d2,
    us* __restrict__ d3, us* __restrict__ d4,
    const float* __restrict__ x,
    const float* __restrict__ ga, const float* __restrict__ ba,
    const float* __restrict__ gb, const float* __restrict__ bb,
    us* __restrict__ outA, us* __restrict__ outB,
    unsigned int* __restrict__ ctr)
{
    int bidx = blockIdx.x;
    int t = threadIdx.x;
    if (bidx == 0 && t == 0) *ctr = 0u;
    if (bidx < 6144) {
        const float* src; us* dst; int blk;
        if (bidx < 1024)      { src = s0; dst = d0; blk = bidx; }
        else if (bidx < 2048) { src = s1; dst = d1; blk = bidx - 1024; }
        else if (bidx < 3072) { src = s2; dst = d2; blk = bidx - 2048; }
        else if (bidx < 4096) { src = s3; dst = d3; blk = bidx - 3072; }
        else                  { src = s4; dst = d4; blk = bidx - 4096; }
        size_t idx = (size_t)blk * 1024 + t * 4;
        float4 v = *(const float4*)(src + idx);
        us4_t ot;
        ot[0] = f2bf(v.x); ot[1] = f2bf(v.y); ot[2] = f2bf(v.z); ot[3] = f2bf(v.w);
        *(us4_t*)(dst + idx) = ot;
        return;
    }
    int row = bidx - 6144;
    const float* xr = x + (size_t)row * DIMS;
    float4 v = *(const float4*)(xr + t * 4);
    float sum1 = v.x + v.y + v.z + v.w;
    float sumq = v.x * v.x + v.y * v.y + v.z * v.z + v.w * v.w;
#pragma unroll
    for (int o = 32; o > 0; o >>= 1) {
        sum1 += __shfl_down(sum1, o, 64);
        sumq += __shfl_down(sumq, o, 64);
    }
    __shared__ float rs[4], rq[4];
    int wid = t >> 6, lane = t & 63;
    if (lane == 0) { rs[wid] = sum1; rq[wid] = sumq; }
    __syncthreads();
    float T1 = rs[0] + rs[1] + rs[2] + rs[3];
    float T2 = rq[0] + rq[1] + rq[2] + rq[3];
    float mean = T1 * (1.0f / DIMS);
    float var  = T2 * (1.0f / DIMS) - mean * mean;
    float inv  = 1.0f / sqrtf(var + 1e-5f);
    float4 vga = *(const float4*)(ga + t * 4);
    float4 vba = *(const float4*)(ba + t * 4);
    float4 vgb = *(const float4*)(gb + t * 4);
    float4 vbb = *(const float4*)(bb + t * 4);
    float nx = (v.x - mean) * inv, ny = (v.y - mean) * inv;
    float nz = (v.z - mean) * inv, nw = (v.w - mean) * inv;
    us4_t oa, ob;
    oa[0] = f2bf(nx * vga.x + vba.x); oa[1] = f2bf(ny * vga.y + vba.y);
    oa[2] = f2bf(nz * vga.z + vba.z); oa[3] = f2bf(nw * vga.w + vba.w);
    ob[0] = f2bf(nx * vgb.x + vbb.x); ob[1] = f2bf(ny * vgb.y + vbb.y);
    ob[2] = f2bf(nz * vgb.z + vbb.z); ob[3] = f2bf(nw * vgb.w + vbb.w);
    *(us4_t*)(outA + (size_t)row * DIMS + t * 4) = oa;
    *(us4_t*)(outB + (size_t)row * DIMS + t * 4) = ob;
}

// ------------- bf16 MFMA GEMM, BM=128 BN=64 BK=64, 4 waves (64x32/wave) ----
static __device__ __forceinline__ void gemm128_body(
    const us* __restrict__ A, int lda,
    const us* __restrict__ W, int ldw,
    const float* __restrict__ bias,
    us* __restrict__ Cp, int ldc, int K,
    int bm, int bn, us* As, us* Bs)
{
    int tid = threadIdx.x;
    int w = tid >> 6, l = tid & 63, l15 = l & 15, lhi = l >> 4;
    int wr = w >> 1, wc = w & 1;
    f32x4 acc[4][2];
#pragma unroll
    for (int m = 0; m < 4; ++m) { acc[m][0] = (f32x4){0,0,0,0}; acc[m][1] = (f32x4){0,0,0,0}; }
    int srow = tid >> 3;
    int scol8 = tid & 7;
    int sl = (scol8 ^ (srow & 7)) * 8;
    const us* Ap = A + (size_t)(bm + srow) * lda + scol8 * 8;
    const us* Wpt = W + (size_t)(bn + srow) * ldw + scol8 * 8;
    us8_t a0 = *(const us8_t*)(Ap);
    us8_t a1 = *(const us8_t*)(Ap + (size_t)32 * lda);
    us8_t a2 = *(const us8_t*)(Ap + (size_t)64 * lda);
    us8_t a3 = *(const us8_t*)(Ap + (size_t)96 * lda);
    us8_t b0 = *(const us8_t*)(Wpt);
    us8_t b1 = *(const us8_t*)(Wpt + (size_t)32 * ldw);
    for (int kt = 0; kt < K; kt += 64) {
        __syncthreads();
        *(us8_t*)&As[(srow +  0) * 64 + sl] = a0;
        *(us8_t*)&As[(srow + 32) * 64 + sl] = a1;
        *(us8_t*)&As[(srow + 64) * 64 + sl] = a2;
        *(us8_t*)&As[(srow + 96) * 64 + sl] = a3;
        *(us8_t*)&Bs[(srow +  0) * 64 + sl] = b0;
        *(us8_t*)&Bs[(srow + 32) * 64 + sl] = b1;
        __syncthreads();
        if (kt + 64 < K) {
            a0 = *(const us8_t*)(Ap + kt + 64);
            a1 = *(const us8_t*)(Ap + (size_t)32 * lda + kt + 64);
            a2 = *(const us8_t*)(Ap + (size_t)64 * lda + kt + 64);
            a3 = *(const us8_t*)(Ap + (size_t)96 * lda + kt + 64);
            b0 = *(const us8_t*)(Wpt + kt + 64);
            b1 = *(const us8_t*)(Wpt + (size_t)32 * ldw + kt + 64);
        }
#pragma unroll
        for (int kk = 0; kk < 2; ++kk) {
            int xo = ((kk * 4 + lhi) ^ (l15 & 7)) * 8;
            us8_t af[4], bfr[2];
#pragma unroll
            for (int m = 0; m < 4; ++m)
                af[m] = *(const us8_t*)&As[(wr * 64 + m * 16 + l15) * 64 + xo];
#pragma unroll
            for (int n = 0; n < 2; ++n)
                bfr[n] = *(const us8_t*)&Bs[(wc * 32 + n * 16 + l15) * 64 + xo];
#pragma unroll
            for (int m = 0; m < 4; ++m)
#pragma unroll
                for (int n = 0; n < 2; ++n)
                    acc[m][n] = mfma16(af[m], bfr[n], acc[m][n]);
        }
    }
    float bvv[2] = {0.f, 0.f};
    if (bias) {
#pragma unroll
        for (int n = 0; n < 2; ++n)
            bvv[n] = bias[bn + wc * 32 + n * 16 + l15];
    }
#pragma unroll
    for (int m = 0; m < 4; ++m) {
#pragma unroll
        for (int n = 0; n < 2; ++n) {
            int row = bm + wr * 64 + m * 16 + lhi * 4;
            int col = bn + wc * 32 + n * 16 + l15;
            unsigned int p01 = pk2bf(acc[m][n][0] + bvv[n], acc[m][n][1] + bvv[n]);
            unsigned int p23 = pk2bf(acc[m][n][2] + bvv[n], acc[m][n][3] + bvv[n]);
            Cp[(size_t)(row + 0) * ldc + col] = (us)p01;
            Cp[(size_t)(row + 1) * ldc + col] = (us)(p01 >> 16);
            Cp[(size_t)(row + 2) * ldc + col] = (us)p23;
            Cp[(size_t)(row + 3) * ldc + col] = (us)(p23 >> 16);
        }
    }
}

// q,k,v in one launch: blockIdx.x selects matrix (16 n-tiles each)
__global__ __launch_bounds__(256) void gemm_qkv(
    const us* __restrict__ A,
    const us* __restrict__ Wq, const us* __restrict__ Wk, const us* __restrict__ Wv,
    const float* __restrict__ bq, const float* __restrict__ bv,
    us* __restrict__ qo, us* __restrict__ ko, us* __restrict__ vo)
{
    __shared__ __align__(16) us As[128 * 64];
    __shared__ __align__(16) us Bs[64 * 64];
    int which = blockIdx.x >> 4;
    int bn = (blockIdx.x & 15) * 64, bm = blockIdx.y * 128;
    const us* W = (which == 0) ? Wq : ((which == 1) ? Wk : Wv);
    const float* bias2 = (which == 0) ? bq : ((which == 2) ? bv : nullptr);
    us* Out = (which == 0) ? qo : ((which == 1) ? ko : vo);
    gemm128_body(A, DIMS, W, DIMS, bias2, Out, DIMS, DIMS, bm, bn, As, Bs);
}

// ---------------- 64x64-tile GEMM, bf16 out (Wc) ---------------------------
__global__ __launch_bounds__(256) void gemm_bf16out(
    const us* __restrict__ A, int lda,
    const us* __restrict__ W, int ldw,
    const float* __restrict__ bias,
    us* __restrict__ Cp, int ldc, int K)
{
    __shared__ __align__(16) us As[64 * 64];
    __shared__ __align__(16) us Bs[64 * 64];
    int tid = threadIdx.x;
    int w = tid >> 6, l = tid & 63, l15 = l & 15, lhi = l >> 4;
    int wr = w >> 1, wc = w & 1;
    int bm = blockIdx.y * 64, bn = blockIdx.x * 64;
    f32x4 acc[2][2] = {{{0,0,0,0},{0,0,0,0}},{{0,0,0,0},{0,0,0,0}}};
    int srow = tid >> 3;
    int scol8 = tid & 7;
    const us* Ap = A + (size_t)(bm + srow) * lda + scol8 * 8;
    const us* Wpt = W + (size_t)(bn + srow) * ldw + scol8 * 8;
    int sl = (scol8 ^ (srow & 7)) * 8;
    us8_t a0 = *(const us8_t*)(Ap);
    us8_t a1 = *(const us8_t*)(Ap + (size_t)32 * lda);
    us8_t b0 = *(const us8_t*)(Wpt);
    us8_t b1 = *(const us8_t*)(Wpt + (size_t)32 * ldw);
    for (int kt = 0; kt < K; kt += 64) {
        __syncthreads();
        *(us8_t*)&As[srow * 64 + sl] = a0;
        *(us8_t*)&As[(srow + 32) * 64 + sl] = a1;
        *(us8_t*)&Bs[srow * 64 + sl] = b0;
        *(us8_t*)&Bs[(srow + 32) * 64 + sl] = b1;
        __syncthreads();
        if (kt + 64 < K) {
            a0 = *(const us8_t*)(Ap + kt + 64);
            a1 = *(const us8_t*)(Ap + (size_t)32 * lda + kt + 64);
            b0 = *(const us8_t*)(Wpt + kt + 64);
            b1 = *(const us8_t*)(Wpt + (size_t)32 * ldw + kt + 64);
        }
#pragma unroll
        for (int kk = 0; kk < 2; ++kk) {
            int xo = ((kk * 4 + lhi) ^ (l15 & 7)) * 8;
            us8_t af[2], bfr[2];
#pragma unroll
            for (int m = 0; m < 2; ++m)
                af[m] = *(const us8_t*)&As[(wr * 32 + m * 16 + l15) * 64 + xo];
#pragma unroll
            for (int n = 0; n < 2; ++n)
                bfr[n] = *(const us8_t*)&Bs[(wc * 32 + n * 16 + l15) * 64 + xo];
#pragma unroll
            for (int m = 0; m < 2; ++m)
#pragma unroll
                for (int n = 0; n < 2; ++n)
                    acc[m][n] = mfma16(af[m], bfr[n], acc[m][n]);
        }
    }
    float bvv[2];
#pragma unroll
    for (int n = 0; n < 2; ++n)
        bvv[n] = bias[bn + wc * 32 + n * 16 + l15];
#pragma unroll
    for (int m = 0; m < 2; ++m) {
#pragma unroll
        for (int n = 0; n < 2; ++n) {
            int row = bm + wr * 32 + m * 16 + lhi * 4;
            int col = bn + wc * 32 + n * 16 + l15;
            unsigned int p01 = pk2bf(acc[m][n][0] + bvv[n], acc[m][n][1] + bvv[n]);
            unsigned int p23 = pk2bf(acc[m][n][2] + bvv[n], acc[m][n][3] + bvv[n]);
            Cp[(size_t)(row + 0) * ldc + col] = (us)p01;
            Cp[(size_t)(row + 1) * ldc + col] = (us)(p01 >> 16);
            Cp[(size_t)(row + 2) * ldc + col] = (us)p23;
            Cp[(size_t)(row + 3) * ldc + col] = (us)(p23 >> 16);
        }
    }
}

// ---------------- 64x64-tile GEMM, f32 out (Wo) ----------------------------
__global__ __launch_bounds__(256) void gemm_f32out(
    const us* __restrict__ A, int lda,
    const us* __restrict__ W, int ldw,
    const float* __restrict__ bias,
    float* __restrict__ Cp, int ldc, int K)
{
    __shared__ __align__(16) us As[64 * 64];
    __shared__ __align__(16) us Bs[64 * 64];
    int tid = threadIdx.x;
    int w = tid >> 6, l = tid & 63, l15 = l & 15, lhi = l >> 4;
    int wr = w >> 1, wc = w & 1;
    int bm = blockIdx.y * 64, bn = blockIdx.x * 64;
    f32x4 acc[2][2] = {{{0,0,0,0},{0,0,0,0}},{{0,0,0,0},{0,0,0,0}}};
    int srow = tid >> 3;
    int scol8 = tid & 7;
    const us* Ap = A + (size_t)(bm + srow) * lda + scol8 * 8;
    const us* Wpt = W + (size_t)(bn + srow) * ldw + scol8 * 8;
    int sl = (scol8 ^ (srow & 7)) * 8;
    us8_t a0 = *(const us8_t*)(Ap);
    us8_t a1 = *(const us8_t*)(Ap + (size_t)32 * lda);
    us8_t b0 = *(const us8_t*)(Wpt);
    us8_t b1 = *(const us8_t*)(Wpt + (size_t)32 * ldw);
    for (int kt = 0; kt < K; kt += 64) {
        __syncthreads();
        *(us8_t*)&As[srow * 64 + sl] = a0;
        *(us8_t*)&As[(srow + 32) * 64 + sl] = a1;
        *(us8_t*)&Bs[srow * 64 + sl] = b0;
        *(us8_t*)&Bs[(srow + 32) * 64 + sl] = b1;
        __syncthreads();
        if (kt + 64 < K) {
            a0 = *(const us8_t*)(Ap + kt + 64);
            a1 = *(const us8_t*)(Ap + (size_t)32 * lda + kt + 64);
            b0 = *(const us8_t*)(Wpt + kt + 64);
            b1 = *(const us8_t*)(Wpt + (size_t)32 * ldw + kt + 64);
        }
#pragma unroll
        for (int kk = 0; kk < 2; ++kk) {
            int xo = ((kk * 4 + lhi) ^ (l15 & 7)) * 8;
            us8_t af[2], bfr[2];
#pragma unroll
            for (int m = 0; m < 2; ++m)
                af[m] = *(const us8_t*)&As[(wr * 32 + m * 16 + l15) * 64 + xo];
#pragma unroll
            for (int n = 0; n < 2; ++n)
                bfr[n] = *(const us8_t*)&Bs[(wc * 32 + n * 16 + l15) * 64 + xo];
#pragma unroll
            for (int m = 0; m < 2; ++m)
#pragma unroll
                for (int n = 0; n < 2; ++n)
                    acc[m][n] = mfma16(af[m], bfr[n], acc[m][n]);
        }
    }
    float bvv[2];
#pragma unroll
    for (int n = 0; n < 2; ++n)
        bvv[n] = bias[bn + wc * 32 + n * 16 + l15];
#pragma unroll
    for (int m = 0; m < 2; ++m) {
#pragma unroll
        for (int n = 0; n < 2; ++n) {
            int row = bm + wr * 32 + m * 16 + lhi * 4;
            int col = bn + wc * 32 + n * 16 + l15;
#pragma unroll
            for (int r = 0; r < 4; ++r)
                Cp[(size_t)(row + r) * ldc + col] = acc[m][n][r] + bvv[n];
        }
    }
}

// ------- MFMA flash attention, split-K, 8 waves, Pt + tr-read, XCD map -----
// P LDS layout (per wave, 1024 us): for P[q][key], key = 32*kk + 8*h + jj:
//   idx = kk*512 + (jj>=4)*256 + h*64 + (jj&3)*16 + q
// tr-read with per-lane addr = base + l*8 delivers (m156):
//   lane l, elem j = region_us[(l>>4)*64 + j*16 + (l&15)]
//   = P[q=l15][key = 32kk + 8*lhi + 4*half + j]  -> exact PV A-frag.
template <int LOCAL>
__global__ __launch_bounds__(512) void attn_mfma(
    const us* __restrict__ Q, const us* __restrict__ K,
    const us* __restrict__ V, us* __restrict__ O, int ldo,
    const float* __restrict__ span)
{
    __shared__ __align__(16) us Ks[2][64 * 64];   // [half][key][d] swizzled
    __shared__ __align__(16) us Vt[2][64 * 64];   // [half][d][key] swizzled
    __shared__ __align__(16) us Ps[8][1024];      // per-wave P in tr-read layout

    int bid = blockIdx.x;
    int xcd = bid & 7, slot = bid >> 3;
    int p = xcd + 8 * (slot >> 4);
    int q0blk = (slot & 15) * 64;
    int h = p & 15, b = p >> 4;

    int tid = threadIdx.x;
    int w = tid >> 6, l = tid & 63;
    int l15 = l & 15, lhi = l >> 4;
    int wq = w & 3, wk = w >> 2;

    float scale; int eff;
    if (LOCAL) { scale = span[1] * LOG2E; eff = (int)span[0]; }
    else       { scale = LOG2E / 64.0f; eff = S_LEN; }
    int ntiles = LOCAL ? ((eff + 63) >> 6) : 16;
    int nIter = (ntiles + 1) >> 1;

    int qrow = q0blk + wq * 16 + l15;
    const us* qptr = Q + ((size_t)(b * S_LEN + qrow)) * DIMS + h * HD + lhi * 8;
    us8_t qf[2];
    qf[0] = *(const us8_t*)(qptr);
    qf[1] = *(const us8_t*)(qptr + 32);

    f32x4 o[4] = {{0,0,0,0},{0,0,0,0},{0,0,0,0},{0,0,0,0}};
    float m_r[4] = {-1e30f, -1e30f, -1e30f, -1e30f};
    float l_r[4] = {0.f, 0.f, 0.f, 0.f};

    int half = tid >> 8;
    int t0 = tid & 255;
    int krow = t0 >> 3, kcol8 = t0 & 7;
    int ksl = (kcol8 ^ (krow & 7)) * 8;
    int vkb = t0 & 15, vdb = t0 >> 4;
    const us* Kb = K + ((size_t)(b * S_LEN)) * DIMS + h * HD;
    const us* Vb = V + ((size_t)(b * S_LEN)) * DIMS + h * HD;

    unsigned pbase = (unsigned)(unsigned long long)&Ps[w][0];
    unsigned paddr = pbase + (unsigned)(l * 8);

    us8_t kc0, kc1;
    us4_t vr0, vr1, vr2, vr3;
    if (half < ntiles) {
        const us* kp = Kb + (size_t)(half * 64 + krow) * DIMS + kcol8 * 8;
        kc0 = *(const us8_t*)kp;
        kc1 = *(const us8_t*)(kp + (size_t)32 * DIMS);
        const us* vp = Vb + (size_t)(half * 64 + vkb * 4) * DIMS + vdb * 4;
        vr0 = *(const us4_t*)(vp);
        vr1 = *(const us4_t*)(vp + DIMS);
        vr2 = *(const us4_t*)(vp + 2 * DIMS);
        vr3 = *(const us4_t*)(vp + 3 * DIMS);
    }

    for (int i = 0; i < nIter; ++i) {
        __syncthreads();
        if (2 * i + half < ntiles) {
            *(us8_t*)&Ks[half][krow * 64 + ksl] = kc0;
            *(us8_t*)&Ks[half][(krow + 32) * 64 + ksl] = kc1;
#pragma unroll
            for (int j = 0; j < 4; ++j) {
                int d = vdb * 4 + j;
                us4_t wv;
                wv[0] = vr0[j]; wv[1] = vr1[j]; wv[2] = vr2[j]; wv[3] = vr3[j];
                int slotv = (vkb >> 1) ^ (d & 7);
                *(us4_t*)&Vt[half][d * 64 + slotv * 8 + (vkb & 1) * 4] = wv;
            }
        }
        __syncthreads();
        int nt2 = 2 * (i + 1) + half;
        if (nt2 < ntiles) {
            const us* kp = Kb + (size_t)(nt2 * 64 + krow) * DIMS + kcol8 * 8;
            kc0 = *(const us8_t*)kp;
            kc1 = *(const us8_t*)(kp + (size_t)32 * DIMS);
            const us* vp = Vb + (size_t)(nt2 * 64 + vkb * 4) * DIMS + vdb * 4;
            vr0 = *(const us4_t*)(vp);
            vr1 = *(const us4_t*)(vp + DIMS);
            vr2 = *(const us4_t*)(vp + 2 * DIMS);
            vr3 = *(const us4_t*)(vp + 3 * DIMS);
        }
        int kt = 2 * i + wk;
        if (kt < ntiles) {
            f32x4 s4[4] = {{0,0,0,0},{0,0,0,0},{0,0,0,0},{0,0,0,0}};
            __builtin_amdgcn_s_setprio(1);
#pragma unroll
            for (int kk = 0; kk < 2; ++kk) {
                int xo = ((kk * 4 + lhi) ^ (l15 & 7)) * 8;
#pragma unroll
                for (int n = 0; n < 4; ++n) {
                    us8_t bk = *(const us8_t*)&Ks[wk][(n * 16 + l15) * 64 + xo];
                    s4[n] = mfma16(qf[kk], bk, s4[n]);
                }
            }
            __builtin_amdgcn_s_setprio(0);
#pragma unroll
            for (int n = 0; n < 4; ++n) {
                s4[n] *= scale;
                if (LOCAL) {
                    int key = kt * 64 + n * 16 + l15;
                    if (key >= eff) {
                        s4[n][0] = -1e30f; s4[n][1] = -1e30f;
                        s4[n][2] = -1e30f; s4[n][3] = -1e30f;
                    }
                }
            }
            float tl[4];
#pragma unroll
            for (int r = 0; r < 4; ++r)
                tl[r] = fmaxf(fmaxf(s4[0][r], s4[1][r]), fmaxf(s4[2][r], s4[3][r]));
            int ex = (tl[0] > m_r[0] + 11.5f) | (tl[1] > m_r[1] + 11.5f) |
                     (tl[2] > m_r[2] + 11.5f) | (tl[3] > m_r[3] + 11.5f);
            if (__any(ex)) {
#pragma unroll
                for (int msk = 1; msk <= 8; msk <<= 1) {
#pragma unroll
                    for (int r = 0; r < 4; ++r)
                        tl[r] = fmaxf(tl[r], __shfl_xor(tl[r], msk, 64));
                }
                float fac[4];
#pragma unroll
                for (int r = 0; r < 4; ++r) {
                    float mn = fmaxf(m_r[r], tl[r]);
                    fac[r] = exp2f(m_r[r] - mn);
                    m_r[r] = mn;
                    l_r[r] *= fac[r];
                }
#pragma unroll
                for (int n = 0; n < 4; ++n) {
                    o[n][0] *= fac[0]; o[n][1] *= fac[1];
                    o[n][2] *= fac[2]; o[n][3] *= fac[3];
                }
            }
#pragma unroll
            for (int n = 0; n < 4; ++n) {
                float p0 = exp2f(s4[n][0] - m_r[0]);
                float p1 = exp2f(s4[n][1] - m_r[1]);
                float p2 = exp2f(s4[n][2] - m_r[2]);
                float p3 = exp2f(s4[n][3] - m_r[3]);
                l_r[0] += p0; l_r[1] += p1; l_r[2] += p2; l_r[3] += p3;
                unsigned int p01 = pk2bf(p0, p1);
                unsigned int p23 = pk2bf(p2, p3);
                int idx = (n >> 1) * 512 + ((l15 & 4) ? 256 : 0)
                        + ((n & 1) * 2 + (l15 >> 3)) * 64 + (l15 & 3) * 16 + lhi * 4;
                *(uint2*)&Ps[w][idx] = make_uint2(p01, p23);
            }
            unsigned long long ta0, ta1, ta2, ta3;
            asm volatile(
                "ds_read_b64_tr_b16 %0, %4\n\t"
                "ds_read_b64_tr_b16 %1, %4 offset:512\n\t"
                "ds_read_b64_tr_b16 %2, %4 offset:1024\n\t"
                "ds_read_b64_tr_b16 %3, %4 offset:1536\n\t"
                "s_waitcnt lgkmcnt(0)"
                : "=&v"(ta0), "=&v"(ta1), "=&v"(ta2), "=&v"(ta3)
                : "v"(paddr)
                : "memory");
            __builtin_amdgcn_sched_barrier(0);
            u32x4 w0 = {(unsigned)ta0, (unsigned)(ta0 >> 32),
                        (unsigned)ta1, (unsigned)(ta1 >> 32)};
            u32x4 w1 = {(unsigned)ta2, (unsigned)(ta2 >> 32),
                        (unsigned)ta3, (unsigned)(ta3 >> 32)};
            us8_t pa0 = __builtin_bit_cast(us8_t, w0);
            us8_t pa1 = __builtin_bit_cast(us8_t, w1);
            __builtin_amdgcn_s_setprio(1);
#pragma unroll
            for (int kk = 0; kk < 2; ++kk) {
                int xo = ((kk * 4 + lhi) ^ (l15 & 7)) * 8;
                us8_t pa = kk ? pa1 : pa0;
#pragma unroll
                for (int n = 0; n < 4; ++n) {
                    us8_t vb = *(const us8_t*)&Vt[wk][(n * 16 + l15) * 64 + xo];
                    o[n] = mfma16(pa, vb, o[n]);
                }
            }
            __builtin_amdgcn_s_setprio(0);
        }
    }

#pragma unroll
    for (int msk = 1; msk <= 8; msk <<= 1) {
#pragma unroll
        for (int r = 0; r < 4; ++r)
            l_r[r] += __shfl_xor(l_r[r], msk, 64);
    }

    __syncthreads();
    float* obuf = (float*)&Ks[0][0];
    float* mlb  = (float*)&Vt[0][0];
    if (wk == 1) {
#pragma unroll
        for (int n = 0; n < 4; ++n)
#pragma unroll
            for (int r = 0; r < 4; ++r)
                obuf[wq * 1024 + (lhi * 4 + r) * 64 + n * 16 + l15] = o[n][r];
        if (l15 == 0) {
#pragma unroll
            for (int r = 0; r < 4; ++r) {
                mlb[wq * 32 + (lhi * 4 + r) * 2 + 0] = m_r[r];
                mlb[wq * 32 + (lhi * 4 + r) * 2 + 1] = l_r[r];
            }
        }
    }
    __syncthreads();
    if (wk == 0) {
        float f0[4], f1[4], rcp[4];
#pragma unroll
        for (int r = 0; r < 4; ++r) {
            int row = lhi * 4 + r;
            float m1 = mlb[wq * 32 + row * 2 + 0];
            float l1 = mlb[wq * 32 + row * 2 + 1];
            float ms = fmaxf(m_r[r], m1);
            f0[r] = exp2f(m_r[r] - ms);
            f1[r] = exp2f(m1 - ms);
            rcp[r] = 1.0f / (l_r[r] * f0[r] + l1 * f1[r]);
        }
#pragma unroll
        for (int n = 0; n < 4; ++n) {
            float vv[4];
#pragma unroll
            for (int r = 0; r < 4; ++r) {
                int row = q0blk + wq * 16 + lhi * 4 + r;
                float val = (o[n][r] * f0[r] +
                             obuf[wq * 1024 + (lhi * 4 + r) * 64 + n * 16 + l15] * f1[r]) * rcp[r];
                if (LOCAL && row >= eff) val = 0.0f;
                vv[r] = val;
            }
            int row0 = q0blk + wq * 16 + lhi * 4;
            unsigned int p01 = pk2bf(vv[0], vv[1]);
            unsigned int p23 = pk2bf(vv[2], vv[3]);
            size_t base = ((size_t)(b * S_LEN + row0)) * ldo + h * HD + n * 16 + l15;
            O[base + 0 * ldo] = (us)p01;
            O[base + 1 * ldo] = (us)(p01 >> 16);
            O[base + 2 * ldo] = (us)p23;
            O[base + 3 * ldo] = (us)(p23 >> 16);
        }
    }
}

// ------- span predictor, fused (64 blocks; last block finalizes) -----------
__global__ __launch_bounds__(256) void span_fused(
    const us* __restrict__ gout, const float* __restrict__ Wp,
    const float* __restrict__ bp,
    float* __restrict__ partials, float* __restrict__ spanbuf,
    unsigned int* __restrict__ ctr)
{
    int slice = blockIdx.x;   // 0..31, 32 rows each
    int b = blockIdx.y;
    int t = threadIdx.x;
    float4 wp = *(const float4*)(Wp + t * 4);
    float acc = 0;
    int srow0 = slice * 32;
    for (int s = srow0; s < srow0 + 32; ++s) {
        us4_t g = *(const us4_t*)(gout + (size_t)(b * S_LEN + s) * 2048 + t * 4);
        acc += bf2f(g[0]) * wp.x + bf2f(g[1]) * wp.y + bf2f(g[2]) * wp.z + bf2f(g[3]) * wp.w;
    }
#pragma unroll
    for (int o = 32; o > 0; o >>= 1) acc += __shfl_down(acc, o, 64);
    __shared__ float r[4];
    int wid = t >> 6, lane = t & 63;
    if (lane == 0) r[wid] = acc;
    __syncthreads();
    if (t == 0) {
        partials[b * 32 + slice] = r[0] + r[1] + r[2] + r[3];
        __threadfence();
        unsigned int old = atomicAdd(ctr, 1u);
        if (old == 63u) {
            __threadfence();
            float l0 = 0, l1 = 0;
            for (int i = 0; i < 32; ++i) { l0 += partials[i]; l1 += partials[32 + i]; }
            l0 = l0 * (1.0f / 1024.0f) + bp[0];
            l1 = l1 * (1.0f / 1024.0f) + bp[0];
            float sg0 = 1.0f / (1.0f + expf(-l0));
            float sg1 = 1.0f / (1.0f + expf(-l1));
            float sm = 0.5f * (sg0 + sg1);
            int sl = (int)floorf(1024.0f * sm);
            int eff = sl; if (eff > 1024) eff = 1024; if (eff < 1) eff = 1;
            float temp = 1.0f + 0.01f * (1.0f - sm);
            spanbuf[0] = (float)eff;
            spanbuf[1] = 0.35355339059327378f / temp;  // 64^-0.25 / temp
        }
    }
}

extern "C" void kernel_launch(void* const* d_in, const int* in_sizes, int n_in,
                              void* d_out, int out_size, void* d_ws, size_t ws_size,
                              hipStream_t stream)
{
    (void)in_sizes; (void)n_in; (void)out_size; (void)ws_size;
    const float* x   = (const float*)d_in[0];
    const float* lag = (const float*)d_in[1];
    const float* lab = (const float*)d_in[2];
    const float* lbg = (const float*)d_in[3];
    const float* lbb = (const float*)d_in[4];
    const float* Wq  = (const float*)d_in[5];
    const float* bq  = (const float*)d_in[6];
    const float* Wk  = (const float*)d_in[7];
    const float* Wv  = (const float*)d_in[8];
    const float* bv  = (const float*)d_in[9];
    const float* Wc  = (const float*)d_in[10];
    const float* bc  = (const float*)d_in[11];
    const float* Wp  = (const float*)d_in[12];
    const float* bp  = (const float*)d_in[13];
    const float* Wo  = (const float*)d_in[14];
    const float* bo  = (const float*)d_in[15];
    float* out = (float*)d_out;
    us* wsu = (us*)d_ws;

    const size_t NM = (size_t)MROWS * DIMS;      // 2M elements
    us* lnAbf = wsu;
    us* lnBbf = wsu + NM;
    us* gattbf = lnBbf;
    us* qbf   = wsu + 2 * NM;
    us* kbf   = wsu + 3 * NM;
    us* vbf   = wsu + 4 * NM;
    us* combbf = qbf;                // [2048,2048] bf16
    us* Wqbf  = wsu + 5 * NM;
    us* Wkbf  = Wqbf + DIMS * DIMS;
    us* Wvbf  = Wkbf + DIMS * DIMS;
    us* Wcbf  = Wvbf + DIMS * DIMS;
    us* Wobf  = Wcbf + DIMS * DIMS;
    float* partials = (float*)(Wobf + 2 * DIMS * DIMS);   // 64 floats
    float* spanbuf  = partials + 64;
    unsigned int* spanctr = (unsigned int*)(spanbuf + 8);

    // weights cvt + both LNs + counter zero, one launch
    prep_kernel<<<8192, 256, 0, stream>>>(Wq, Wk, Wv, Wc, Wo,
                                          Wqbf, Wkbf, Wvbf, Wcbf, Wobf,
                                          x, lag, lab, lbg, lbb, lnAbf, lnBbf,
                                          spanctr);

    gemm_qkv<<<dim3(48, MROWS / 128), 256, 0, stream>>>(
        lnBbf, Wqbf, Wkbf, Wvbf, bq, bv, qbf, kbf, vbf);

    attn_mfma<0><<<512, 512, 0, stream>>>(qbf, kbf, vbf, gattbf, DIMS, nullptr);

    // g_out -> comb[:, 1024:2048]  (bf16)
    gemm_bf16out<<<dim3(DIMS / 64, MROWS / 64), 256, 0, stream>>>(
        gattbf, DIMS, Wcbf, DIMS, bc, combbf + 1024, 2048, DIMS);

    span_fused<<<dim3(32, BATCH), 256, 0, stream>>>(combbf + 1024, Wp, bp,
                                                    partials, spanbuf, spanctr);

    // l_out -> comb[:, 0:1024]  (bf16)
    attn_mfma<1><<<512, 512, 0, stream>>>(lnAbf, lnAbf, lnAbf, combbf, 2048, spanbuf);

    // out = comb @ Wo^T + bo   (K = 2048, f32 out)
    gemm_f32out<<<dim3(DIMS / 64, MROWS / 64), 256, 0, stream>>>(
        combbf, 2048, Wobf, 2048, bo, out, DIMS, 2 * DIMS);
}